// Round 1
// baseline (2002.865 us; speedup 1.0000x reference)
//
#include <hip/hip_runtime.h>
#include <hip/hip_bf16.h>
#include <math.h>

// ---------------- Problem dims ----------------
#define B       256
// conv1: in (B,3,250,250) -> out (B,6,124,124), k=5 s=2 p=1
#define C1_IC   3
#define C1_OC   6
#define C1_IH   250
#define C1_OH   124
// pool1 -> (B,6,123,123)
#define P1_H    123
// conv2: in (B,6,123,123) -> out (B,15,62,62), k=3 s=2 p=1
#define C2_IC   6
#define C2_OC   15
#define C2_OH   62
// pool2 -> (B,15,61,61) flat 55815
#define P2_H    61
#define FC1_K   55815
#define FC1_N   120
#define FC2_N   84
#define FC3_N   4

#define FC1_CHUNK 512
#define FC1_MT    16

// ---------------- conv1 + ReLU ----------------
__global__ __launch_bounds__(256) void conv1_kernel(
    const float* __restrict__ x, const float* __restrict__ w1,
    const float* __restrict__ b1, float* __restrict__ out) {
    __shared__ float w[C1_OC * C1_IC * 25];
    __shared__ float bias[C1_OC];
    for (int i = threadIdx.x; i < C1_OC * C1_IC * 25; i += blockDim.x) w[i] = w1[i];
    if (threadIdx.x < C1_OC) bias[threadIdx.x] = b1[threadIdx.x];
    __syncthreads();

    int idx = blockIdx.x * blockDim.x + threadIdx.x;
    const int total = B * C1_OC * C1_OH * C1_OH;
    if (idx >= total) return;
    int ox = idx % C1_OH;
    int t  = idx / C1_OH;
    int oy = t % C1_OH;
    t /= C1_OH;
    int o = t % C1_OC;
    int b = t / C1_OC;

    float acc = bias[o];
    int iy0 = oy * 2 - 1, ix0 = ox * 2 - 1;
    const float* wo = &w[o * C1_IC * 25];
    for (int c = 0; c < C1_IC; ++c) {
        const float* xp = x + ((b * C1_IC + c) * C1_IH) * C1_IH;
        const float* wc = wo + c * 25;
        #pragma unroll
        for (int ky = 0; ky < 5; ++ky) {
            int iy = iy0 + ky;
            if ((unsigned)iy >= (unsigned)C1_IH) continue;
            const float* row = xp + iy * C1_IH;
            #pragma unroll
            for (int kx = 0; kx < 5; ++kx) {
                int ix = ix0 + kx;
                if ((unsigned)ix >= (unsigned)C1_IH) continue;
                acc += row[ix] * wc[ky * 5 + kx];
            }
        }
    }
    out[idx] = fmaxf(acc, 0.f);
}

// ---------------- maxpool 2x2 stride 1 (square planes) ----------------
__global__ __launch_bounds__(256) void maxpool_kernel(
    const float* __restrict__ in, float* __restrict__ out, int H, int total) {
    int idx = blockIdx.x * blockDim.x + threadIdx.x;
    if (idx >= total) return;
    int OW = H - 1;
    int ox = idx % OW;
    int t  = idx / OW;
    int oy = t % OW;
    int plane = t / OW;
    const float* p = in + (plane * H + oy) * H + ox;
    out[idx] = fmaxf(fmaxf(p[0], p[1]), fmaxf(p[H], p[H + 1]));
}

// ---------------- conv2 + ReLU ----------------
__global__ __launch_bounds__(256) void conv2_kernel(
    const float* __restrict__ in, const float* __restrict__ w2,
    const float* __restrict__ b2, float* __restrict__ out) {
    __shared__ float w[C2_OC * C2_IC * 9];
    __shared__ float bias[C2_OC];
    for (int i = threadIdx.x; i < C2_OC * C2_IC * 9; i += blockDim.x) w[i] = w2[i];
    if (threadIdx.x < C2_OC) bias[threadIdx.x] = b2[threadIdx.x];
    __syncthreads();

    int idx = blockIdx.x * blockDim.x + threadIdx.x;
    const int total = B * C2_OC * C2_OH * C2_OH;
    if (idx >= total) return;
    int ox = idx % C2_OH;
    int t  = idx / C2_OH;
    int oy = t % C2_OH;
    t /= C2_OH;
    int o = t % C2_OC;
    int b = t / C2_OC;

    float acc = bias[o];
    int iy0 = oy * 2 - 1, ix0 = ox * 2 - 1;
    for (int c = 0; c < C2_IC; ++c) {
        const float* ip = in + ((b * C2_IC + c) * P1_H) * P1_H;
        const float* wc = w + (o * C2_IC + c) * 9;
        #pragma unroll
        for (int ky = 0; ky < 3; ++ky) {
            int iy = iy0 + ky;
            if ((unsigned)iy >= (unsigned)P1_H) continue;
            const float* row = ip + iy * P1_H;
            #pragma unroll
            for (int kx = 0; kx < 3; ++kx) {
                int ix = ix0 + kx;
                if ((unsigned)ix >= (unsigned)P1_H) continue;
                acc += row[ix] * wc[ky * 3 + kx];
            }
        }
    }
    out[idx] = fmaxf(acc, 0.f);
}

// ---------------- fc1: split-K GEMM, atomic accumulate ----------------
// A: (B, 55815) row-major (pool2 output). W: (120, 55815) row-major.
// grid = (16 m-tiles, 110 k-chunks), block = 256.
__global__ __launch_bounds__(256) void fc1_kernel(
    const float* __restrict__ A, const float* __restrict__ W,
    float* __restrict__ out) {
    __shared__ float lds[FC1_MT * FC1_CHUNK];
    int m0 = blockIdx.x * FC1_MT;
    int k0 = blockIdx.y * FC1_CHUNK;
    int klen = FC1_K - k0;
    if (klen > FC1_CHUNK) klen = FC1_CHUNK;

    for (int f = threadIdx.x; f < FC1_MT * FC1_CHUNK; f += 256) {
        int r = f >> 9;      // /512
        int c = f & 511;
        float v = 0.f;
        if (c < klen) v = A[(m0 + r) * FC1_K + k0 + c];
        lds[f] = v;
    }
    __syncthreads();

    int t = threadIdx.x;
    if (t >= 240) return;
    int j  = (t < 120) ? t : t - 120;
    int r0 = (t < 120) ? 0 : 8;
    const float* wrow = W + (size_t)j * FC1_K + k0;

    float acc[8] = {0.f, 0.f, 0.f, 0.f, 0.f, 0.f, 0.f, 0.f};
    int klen4 = klen & ~3;
    for (int k = 0; k < klen4; k += 4) {
        float w0 = wrow[k], w1v = wrow[k + 1], w2v = wrow[k + 2], w3 = wrow[k + 3];
        #pragma unroll
        for (int i = 0; i < 8; ++i) {
            const float4 a = *(const float4*)&lds[(r0 + i) * FC1_CHUNK + k];
            acc[i] += w0 * a.x + w1v * a.y + w2v * a.z + w3 * a.w;
        }
    }
    for (int k = klen4; k < klen; ++k) {
        float wv = wrow[k];
        #pragma unroll
        for (int i = 0; i < 8; ++i)
            acc[i] += wv * lds[(r0 + i) * FC1_CHUNK + k];
    }
    #pragma unroll
    for (int i = 0; i < 8; ++i)
        atomicAdd(&out[(m0 + r0 + i) * FC1_N + j], acc[i]);
}

// ---------------- tail: bias+ReLU, fc2, fc3, quantum head, softmax ----------------
__global__ __launch_bounds__(128) void tail_kernel(
    const float* __restrict__ fc1_raw, const float* __restrict__ fc1_b,
    const float* __restrict__ fc2_w, const float* __restrict__ fc2_b,
    const float* __restrict__ fc3_w, const float* __restrict__ fc3_b,
    const float* __restrict__ qw, float* __restrict__ out) {
    __shared__ float h1[FC1_N];
    __shared__ float h2[FC2_N];
    __shared__ float ang[FC3_N];
    int b = blockIdx.x;
    int t = threadIdx.x;

    if (t < FC1_N) h1[t] = fmaxf(fc1_raw[b * FC1_N + t] + fc1_b[t], 0.f);
    __syncthreads();
    if (t < FC2_N) {
        float acc = fc2_b[t];
        const float* w = fc2_w + t * FC1_N;
        for (int k = 0; k < FC1_N; ++k) acc += h1[k] * w[k];
        h2[t] = fmaxf(acc, 0.f);
    }
    __syncthreads();
    if (t < FC3_N) {
        float acc = fc3_b[t];
        const float* w = fc3_w + t * FC2_N;
        for (int k = 0; k < FC2_N; ++k) acc += h2[k] * w[k];
        ang[t] = acc;
    }
    __syncthreads();
    if (t == 0) {
        // 4-qubit statevector, wire q = bit (3-q)
        float sr[16], si[16];
        #pragma unroll
        for (int i = 0; i < 16; ++i) { sr[i] = 0.f; si[i] = 0.f; }
        sr[0] = 1.f;
        // RX(angles[q]) encoding: [[c,-i s],[-i s,c]]
        for (int q = 0; q < 4; ++q) {
            float th = ang[q] * 0.5f;
            float c = cosf(th), s = sinf(th);
            int mask = 1 << (3 - q);
            #pragma unroll
            for (int i = 0; i < 16; ++i) {
                if (i & mask) continue;
                int i1 = i | mask;
                float a0r = sr[i], a0i = si[i], a1r = sr[i1], a1i = si[i1];
                sr[i]  = c * a0r + s * a1i;
                si[i]  = c * a0i - s * a1r;
                sr[i1] = c * a1r + s * a0i;
                si[i1] = c * a1i - s * a0r;
            }
        }
        int widx = 0;
        for (int d = 0; d < 2; ++d) {
            // RY(w) on every wire: [[c,-s],[s,c]]
            for (int q = 0; q < 4; ++q) {
                float th = qw[widx++] * 0.5f;
                float c = cosf(th), s = sinf(th);
                int mask = 1 << (3 - q);
                #pragma unroll
                for (int i = 0; i < 16; ++i) {
                    if (i & mask) continue;
                    int i1 = i | mask;
                    float a0r = sr[i], a0i = si[i], a1r = sr[i1], a1i = si[i1];
                    sr[i]  = c * a0r - s * a1r;
                    si[i]  = c * a0i - s * a1i;
                    sr[i1] = s * a0r + c * a1r;
                    si[i1] = s * a0i + c * a1i;
                }
            }
            // CZ chain
            for (int q = 0; q < 3; ++q) {
                int m1 = 1 << (3 - q), m2 = 1 << (2 - q);
                #pragma unroll
                for (int i = 0; i < 16; ++i) {
                    if ((i & m1) && (i & m2)) { sr[i] = -sr[i]; si[i] = -si[i]; }
                }
            }
        }
        float l0 = 0.f, l1 = 0.f;
        #pragma unroll
        for (int i = 0; i < 16; ++i) {
            float p = sr[i] * sr[i] + si[i] * si[i];
            l0 += (i & 8) ? -p : p;
            l1 += (i & 4) ? -p : p;
        }
        float m = fmaxf(l0, l1);
        float e0 = expf(l0 - m), e1 = expf(l1 - m);
        float inv = 1.f / (e0 + e1);
        out[b * 2 + 0] = e0 * inv;
        out[b * 2 + 1] = e1 * inv;
    }
}

extern "C" void kernel_launch(void* const* d_in, const int* in_sizes, int n_in,
                              void* d_out, int out_size, void* d_ws, size_t ws_size,
                              hipStream_t stream) {
    const float* x     = (const float*)d_in[0];
    const float* w1    = (const float*)d_in[1];
    const float* b1    = (const float*)d_in[2];
    const float* w2    = (const float*)d_in[3];
    const float* b2    = (const float*)d_in[4];
    const float* fc1_w = (const float*)d_in[5];
    const float* fc1_b = (const float*)d_in[6];
    const float* fc2_w = (const float*)d_in[7];
    const float* fc2_b = (const float*)d_in[8];
    const float* fc3_w = (const float*)d_in[9];
    const float* fc3_b = (const float*)d_in[10];
    const float* qw    = (const float*)d_in[11];
    float* out = (float*)d_out;

    // Workspace layout (aliased):
    //   buf1: conv1 out (94,470,144 B) -> later reused for conv2 out (59 MB)
    //   buf2: pool1     (92,952,576 B) -> later reused for pool2 (57.2 MB)
    //   fc1_raw: 256*120*4 B
    char* ws = (char*)d_ws;
    const size_t OFF1 = 0;
    const size_t OFF2 = (size_t)B * C1_OC * C1_OH * C1_OH * 4;              // 94,470,144
    const size_t OFF3 = OFF2 + (size_t)B * C1_OC * P1_H * P1_H * 4;         // +92,952,576
    float* buf1    = (float*)(ws + OFF1);
    float* buf2    = (float*)(ws + OFF2);
    float* fc1_raw = (float*)(ws + OFF3);

    // 1. conv1 + ReLU: x -> buf1 (B,6,124,124)
    {
        int total = B * C1_OC * C1_OH * C1_OH;
        conv1_kernel<<<(total + 255) / 256, 256, 0, stream>>>(x, w1, b1, buf1);
    }
    // 2. pool1: buf1 -> buf2 (B,6,123,123)
    {
        int total = B * C1_OC * P1_H * P1_H;
        maxpool_kernel<<<(total + 255) / 256, 256, 0, stream>>>(buf1, buf2, C1_OH, total);
    }
    // 3. conv2 + ReLU: buf2 -> buf1 (B,15,62,62)
    {
        int total = B * C2_OC * C2_OH * C2_OH;
        conv2_kernel<<<(total + 255) / 256, 256, 0, stream>>>(buf2, w2, b2, buf1);
    }
    // 4. pool2: buf1 -> buf2 (B,15,61,61) == (B, 55815) fc1 input
    {
        int total = B * C2_OC * P2_H * P2_H;
        maxpool_kernel<<<(total + 255) / 256, 256, 0, stream>>>(buf1, buf2, C2_OH, total);
    }
    // 5. zero fc1 accumulator, then split-K GEMM with atomics
    hipMemsetAsync(fc1_raw, 0, (size_t)B * FC1_N * 4, stream);
    {
        dim3 grid(B / FC1_MT, (FC1_K + FC1_CHUNK - 1) / FC1_CHUNK);
        fc1_kernel<<<grid, 256, 0, stream>>>(buf2, fc1_w, fc1_raw);
    }
    // 6. tail: bias+ReLU, fc2, fc3, quantum head, softmax -> out (B,2)
    tail_kernel<<<B, 128, 0, stream>>>(fc1_raw, fc1_b, fc2_w, fc2_b,
                                       fc3_w, fc3_b, qw, out);
}

// Round 2
// 790.901 us; speedup vs baseline: 2.5324x; 2.5324x over previous
//
#include <hip/hip_runtime.h>
#include <hip/hip_bf16.h>
#include <math.h>

// ---------------- Problem dims ----------------
#define B       256
#define C1_IC   3
#define C1_OC   6
#define C1_IH   250
#define C1_OH   124
#define P1_H    123
#define C2_IC   6
#define C2_OC   15
#define C2_OH   62
#define P2_H    61
#define FC1_K   55815
#define FC1_N   120
#define FC2_N   84
#define FC3_N   4

#define FC1_CHUNK 512
#define FC1_MT    16

// ================= fused conv1 (5x5 s2 p1) + ReLU + maxpool(2,1) =================
// Block: 256 threads = 32x8 conv-output tile. Pool tile = 31x7.
// Grid: (4 x-tiles, 18 y-tiles, 256 batch).
#define T1_IW 67          // input tile cols (2*32+3), odd -> conflict-free
#define T1_IH 19          // input tile rows (2*8+3)
#define T1_ICH (T1_IH * T1_IW)   // 1273

__global__ __launch_bounds__(256) void conv1_pool1_kernel(
    const float* __restrict__ x, const float* __restrict__ w1,
    const float* __restrict__ b1, float* __restrict__ pool1) {
    __shared__ float in_t[C1_IC * T1_ICH];          // 3*19*67 floats
    __shared__ float out_t[C1_OC * 8 * 33];         // conv tile, stride 33 (odd)

    const int tid = threadIdx.x;
    const int px0 = blockIdx.x * 31;
    const int py0 = blockIdx.y * 7;
    const int b   = blockIdx.z;

    // ---- stage input tile (zero-padded) ----
    const int iy_base = 2 * py0 - 1;
    const int ix_base = 2 * px0 - 1;
    for (int f = tid; f < C1_IC * T1_ICH; f += 256) {
        int ch  = f / T1_ICH;
        int rem = f - ch * T1_ICH;
        int row = rem / T1_IW;
        int col = rem - row * T1_IW;
        int iy = iy_base + row, ix = ix_base + col;
        float v = 0.f;
        if ((unsigned)iy < (unsigned)C1_IH && (unsigned)ix < (unsigned)C1_IH)
            v = x[((b * C1_IC + ch) * C1_IH + iy) * C1_IH + ix];
        in_t[f] = v;
    }
    __syncthreads();

    // ---- conv: each thread = one (cy,cx) position, all 6 oc in registers ----
    const int cx = tid & 31;
    const int cy = tid >> 5;
    float acc[C1_OC];
    #pragma unroll
    for (int oc = 0; oc < C1_OC; ++oc) acc[oc] = b1[oc];   // uniform s_load

    #pragma unroll
    for (int c = 0; c < C1_IC; ++c) {
        const float* base = &in_t[c * T1_ICH + (2 * cy) * T1_IW + 2 * cx];
        #pragma unroll
        for (int ky = 0; ky < 5; ++ky) {
            const float* r = base + ky * T1_IW;
            #pragma unroll
            for (int kx = 0; kx < 5; ++kx) {
                float v = r[kx];
                #pragma unroll
                for (int oc = 0; oc < C1_OC; ++oc)
                    acc[oc] += v * w1[(oc * C1_IC + c) * 25 + ky * 5 + kx]; // uniform s_load
            }
        }
    }
    #pragma unroll
    for (int oc = 0; oc < C1_OC; ++oc)
        out_t[(oc * 8 + cy) * 33 + cx] = fmaxf(acc[oc], 0.f);
    __syncthreads();

    // ---- pool 2x2 s1 from LDS, write (B,6,123,123) ----
    if (cx < 31 && cy < 7) {
        int py = py0 + cy, px = px0 + cx;
        if (py < P1_H && px < P1_H) {
            #pragma unroll
            for (int oc = 0; oc < C1_OC; ++oc) {
                const float* p = &out_t[(oc * 8 + cy) * 33 + cx];
                float m = fmaxf(fmaxf(p[0], p[1]), fmaxf(p[33], p[34]));
                pool1[((b * C1_OC + oc) * P1_H + py) * P1_H + px] = m;
            }
        }
    }
}

// ================= fused conv2 (3x3 s2 p1) + ReLU + maxpool(2,1) =================
// Block: 256 threads = 32x8 conv tile, pool tile 31x7.
// Grid: (2, 9, 256).
#define T2_IW 65          // 2*32+1, odd
#define T2_IH 17          // 2*8+1
#define T2_ICH (T2_IH * T2_IW)   // 1105

__global__ __launch_bounds__(256) void conv2_pool2_kernel(
    const float* __restrict__ in, const float* __restrict__ w2,
    const float* __restrict__ b2, float* __restrict__ pool2) {
    __shared__ float in_t[C2_IC * T2_ICH];          // 6*17*65 floats (25.9 KB)
    __shared__ float out_t[C2_OC * 8 * 33];         // 15.5 KB

    const int tid = threadIdx.x;
    const int px0 = blockIdx.x * 31;
    const int py0 = blockIdx.y * 7;
    const int b   = blockIdx.z;

    const int iy_base = 2 * py0 - 1;
    const int ix_base = 2 * px0 - 1;
    for (int f = tid; f < C2_IC * T2_ICH; f += 256) {
        int ch  = f / T2_ICH;
        int rem = f - ch * T2_ICH;
        int row = rem / T2_IW;
        int col = rem - row * T2_IW;
        int iy = iy_base + row, ix = ix_base + col;
        float v = 0.f;
        if ((unsigned)iy < (unsigned)P1_H && (unsigned)ix < (unsigned)P1_H)
            v = in[((b * C2_IC + ch) * P1_H + iy) * P1_H + ix];
        in_t[f] = v;
    }
    __syncthreads();

    const int cx = tid & 31;
    const int cy = tid >> 5;
    float acc[C2_OC];
    #pragma unroll
    for (int oc = 0; oc < C2_OC; ++oc) acc[oc] = b2[oc];

    #pragma unroll
    for (int c = 0; c < C2_IC; ++c) {
        const float* base = &in_t[c * T2_ICH + (2 * cy) * T2_IW + 2 * cx];
        #pragma unroll
        for (int ky = 0; ky < 3; ++ky) {
            const float* r = base + ky * T2_IW;
            #pragma unroll
            for (int kx = 0; kx < 3; ++kx) {
                float v = r[kx];
                #pragma unroll
                for (int oc = 0; oc < C2_OC; ++oc)
                    acc[oc] += v * w2[(oc * C2_IC + c) * 9 + ky * 3 + kx];
            }
        }
    }
    #pragma unroll
    for (int oc = 0; oc < C2_OC; ++oc)
        out_t[(oc * 8 + cy) * 33 + cx] = fmaxf(acc[oc], 0.f);
    __syncthreads();

    if (cx < 31 && cy < 7) {
        int py = py0 + cy, px = px0 + cx;
        if (py < P2_H && px < P2_H) {
            #pragma unroll
            for (int oc = 0; oc < C2_OC; ++oc) {
                const float* p = &out_t[(oc * 8 + cy) * 33 + cx];
                float m = fmaxf(fmaxf(p[0], p[1]), fmaxf(p[33], p[34]));
                pool2[((b * C2_OC + oc) * P2_H + py) * P2_H + px] = m;
            }
        }
    }
}

// ---------------- fc1: split-K GEMM, atomic accumulate ----------------
__global__ __launch_bounds__(256) void fc1_kernel(
    const float* __restrict__ A, const float* __restrict__ W,
    float* __restrict__ out) {
    __shared__ float lds[FC1_MT * FC1_CHUNK];
    int m0 = blockIdx.x * FC1_MT;
    int k0 = blockIdx.y * FC1_CHUNK;
    int klen = FC1_K - k0;
    if (klen > FC1_CHUNK) klen = FC1_CHUNK;

    for (int f = threadIdx.x; f < FC1_MT * FC1_CHUNK; f += 256) {
        int r = f >> 9;
        int c = f & 511;
        float v = 0.f;
        if (c < klen) v = A[(m0 + r) * FC1_K + k0 + c];
        lds[f] = v;
    }
    __syncthreads();

    int t = threadIdx.x;
    if (t >= 240) return;
    int j  = (t < 120) ? t : t - 120;
    int r0 = (t < 120) ? 0 : 8;
    const float* wrow = W + (size_t)j * FC1_K + k0;

    float acc[8] = {0.f, 0.f, 0.f, 0.f, 0.f, 0.f, 0.f, 0.f};
    int klen4 = klen & ~3;
    for (int k = 0; k < klen4; k += 4) {
        float w0 = wrow[k], w1v = wrow[k + 1], w2v = wrow[k + 2], w3 = wrow[k + 3];
        #pragma unroll
        for (int i = 0; i < 8; ++i) {
            const float4 a = *(const float4*)&lds[(r0 + i) * FC1_CHUNK + k];
            acc[i] += w0 * a.x + w1v * a.y + w2v * a.z + w3 * a.w;
        }
    }
    for (int k = klen4; k < klen; ++k) {
        float wv = wrow[k];
        #pragma unroll
        for (int i = 0; i < 8; ++i)
            acc[i] += wv * lds[(r0 + i) * FC1_CHUNK + k];
    }
    #pragma unroll
    for (int i = 0; i < 8; ++i)
        atomicAdd(&out[(m0 + r0 + i) * FC1_N + j], acc[i]);
}

// ---------------- tail: bias+ReLU, fc2, fc3, quantum head, softmax ----------------
__global__ __launch_bounds__(128) void tail_kernel(
    const float* __restrict__ fc1_raw, const float* __restrict__ fc1_b,
    const float* __restrict__ fc2_w, const float* __restrict__ fc2_b,
    const float* __restrict__ fc3_w, const float* __restrict__ fc3_b,
    const float* __restrict__ qw, float* __restrict__ out) {
    __shared__ float h1[FC1_N];
    __shared__ float h2[FC2_N];
    __shared__ float ang[FC3_N];
    int b = blockIdx.x;
    int t = threadIdx.x;

    if (t < FC1_N) h1[t] = fmaxf(fc1_raw[b * FC1_N + t] + fc1_b[t], 0.f);
    __syncthreads();
    if (t < FC2_N) {
        float acc = fc2_b[t];
        const float* w = fc2_w + t * FC1_N;
        for (int k = 0; k < FC1_N; ++k) acc += h1[k] * w[k];
        h2[t] = fmaxf(acc, 0.f);
    }
    __syncthreads();
    if (t < FC3_N) {
        float acc = fc3_b[t];
        const float* w = fc3_w + t * FC2_N;
        for (int k = 0; k < FC2_N; ++k) acc += h2[k] * w[k];
        ang[t] = acc;
    }
    __syncthreads();
    if (t == 0) {
        float sr[16], si[16];
        #pragma unroll
        for (int i = 0; i < 16; ++i) { sr[i] = 0.f; si[i] = 0.f; }
        sr[0] = 1.f;
        for (int q = 0; q < 4; ++q) {
            float th = ang[q] * 0.5f;
            float c = cosf(th), s = sinf(th);
            int mask = 1 << (3 - q);
            #pragma unroll
            for (int i = 0; i < 16; ++i) {
                if (i & mask) continue;
                int i1 = i | mask;
                float a0r = sr[i], a0i = si[i], a1r = sr[i1], a1i = si[i1];
                sr[i]  = c * a0r + s * a1i;
                si[i]  = c * a0i - s * a1r;
                sr[i1] = c * a1r + s * a0i;
                si[i1] = c * a1i - s * a0r;
            }
        }
        int widx = 0;
        for (int d = 0; d < 2; ++d) {
            for (int q = 0; q < 4; ++q) {
                float th = qw[widx++] * 0.5f;
                float c = cosf(th), s = sinf(th);
                int mask = 1 << (3 - q);
                #pragma unroll
                for (int i = 0; i < 16; ++i) {
                    if (i & mask) continue;
                    int i1 = i | mask;
                    float a0r = sr[i], a0i = si[i], a1r = sr[i1], a1i = si[i1];
                    sr[i]  = c * a0r - s * a1r;
                    si[i]  = c * a0i - s * a1i;
                    sr[i1] = s * a0r + c * a1r;
                    si[i1] = s * a0i + c * a1i;
                }
            }
            for (int q = 0; q < 3; ++q) {
                int m1 = 1 << (3 - q), m2 = 1 << (2 - q);
                #pragma unroll
                for (int i = 0; i < 16; ++i) {
                    if ((i & m1) && (i & m2)) { sr[i] = -sr[i]; si[i] = -si[i]; }
                }
            }
        }
        float l0 = 0.f, l1 = 0.f;
        #pragma unroll
        for (int i = 0; i < 16; ++i) {
            float p = sr[i] * sr[i] + si[i] * si[i];
            l0 += (i & 8) ? -p : p;
            l1 += (i & 4) ? -p : p;
        }
        float m = fmaxf(l0, l1);
        float e0 = expf(l0 - m), e1 = expf(l1 - m);
        float inv = 1.f / (e0 + e1);
        out[b * 2 + 0] = e0 * inv;
        out[b * 2 + 1] = e1 * inv;
    }
}

extern "C" void kernel_launch(void* const* d_in, const int* in_sizes, int n_in,
                              void* d_out, int out_size, void* d_ws, size_t ws_size,
                              hipStream_t stream) {
    const float* x     = (const float*)d_in[0];
    const float* w1    = (const float*)d_in[1];
    const float* b1    = (const float*)d_in[2];
    const float* w2    = (const float*)d_in[3];
    const float* b2    = (const float*)d_in[4];
    const float* fc1_w = (const float*)d_in[5];
    const float* fc1_b = (const float*)d_in[6];
    const float* fc2_w = (const float*)d_in[7];
    const float* fc2_b = (const float*)d_in[8];
    const float* fc3_w = (const float*)d_in[9];
    const float* fc3_b = (const float*)d_in[10];
    const float* qw    = (const float*)d_in[11];
    float* out = (float*)d_out;

    // Workspace: pool1 (92,952,576 B) | pool2 (57,154,560 B) | fc1_raw (122,880 B)
    char* ws = (char*)d_ws;
    float* pool1   = (float*)ws;
    float* pool2   = (float*)(ws + (size_t)B * C1_OC * P1_H * P1_H * 4);
    float* fc1_raw = (float*)(ws + (size_t)B * C1_OC * P1_H * P1_H * 4
                                 + (size_t)B * C2_OC * P2_H * P2_H * 4);

    // 1. fused conv1+ReLU+pool1: x -> pool1 (B,6,123,123)
    conv1_pool1_kernel<<<dim3(4, 18, B), 256, 0, stream>>>(x, w1, b1, pool1);
    // 2. fused conv2+ReLU+pool2: pool1 -> pool2 (B,15,61,61) = (B,55815)
    conv2_pool2_kernel<<<dim3(2, 9, B), 256, 0, stream>>>(pool1, w2, b2, pool2);
    // 3. fc1 split-K GEMM with atomics
    hipMemsetAsync(fc1_raw, 0, (size_t)B * FC1_N * 4, stream);
    {
        dim3 grid(B / FC1_MT, (FC1_K + FC1_CHUNK - 1) / FC1_CHUNK);
        fc1_kernel<<<grid, 256, 0, stream>>>(pool2, fc1_w, fc1_raw);
    }
    // 4. tail
    tail_kernel<<<B, 128, 0, stream>>>(fc1_raw, fc1_b, fc2_w, fc2_b,
                                       fc3_w, fc3_b, qw, out);
}

// Round 3
// 693.308 us; speedup vs baseline: 2.8889x; 1.1408x over previous
//
#include <hip/hip_runtime.h>
#include <hip/hip_bf16.h>
#include <math.h>

// ---------------- Problem dims ----------------
#define B       256
#define C1_IC   3
#define C1_OC   6
#define C1_IH   250
#define P1_H    123
#define C2_IC   6
#define C2_OC   15
#define P2_H    61
#define FC1_K   55815
#define FC1_N   120
#define FC2_N   84

// fc1 MFMA GEMM config
#define KP        57344            // K padded to 128*448
#define FC1_SPLIT 128
#define FC1_KC    (KP / FC1_SPLIT) // 448

typedef __attribute__((ext_vector_type(8))) short bf16x8;
typedef __attribute__((ext_vector_type(4))) float f32x4;

// ================= conv1 (5x5 s2 p1) + ReLU + pool(2,1) =================
// conv tile 32x16 (thread = 1 col x 2 rows), pool tile 31x15. Grid (4,9,256).
#define T1_IW   67
#define T1_ROWS 35
#define T1_ICH  (T1_IW * T1_ROWS)   // 2345

__global__ __launch_bounds__(256) void conv1_pool1_kernel(
    const float* __restrict__ x, const float* __restrict__ w1,
    const float* __restrict__ b1, float* __restrict__ pool1) {
    __shared__ float in_t[C1_IC * T1_ICH];     // 7035 fl = 28.1 KB
    __shared__ float wlds[75 * 8];             // [k][oc pad 8]
    __shared__ float out_t[C1_OC * 16 * 33];   // 12.7 KB

    const int tid = threadIdx.x;
    const int cx0 = blockIdx.x * 31;   // conv col base
    const int cy0 = blockIdx.y * 15;   // conv row base
    const int b   = blockIdx.z;

    for (int f = tid; f < 600; f += 256) {
        int oc = f & 7, k = f >> 3;
        wlds[f] = (oc < C1_OC) ? w1[oc * 75 + k] : 0.f;
    }
    const int iy0 = 2 * cy0 - 1, ix0 = 2 * cx0 - 1;
    for (int f = tid; f < C1_IC * T1_ICH; f += 256) {
        int ch = f / T1_ICH, rem = f - ch * T1_ICH;
        int row = rem / T1_IW, col = rem - row * T1_IW;
        int iy = iy0 + row, ix = ix0 + col;
        float v = 0.f;
        if ((unsigned)iy < (unsigned)C1_IH && (unsigned)ix < (unsigned)C1_IH)
            v = x[((b * C1_IC + ch) * C1_IH + iy) * C1_IH + ix];
        in_t[f] = v;
    }
    __syncthreads();

    const int cx = tid & 31, cyp = tid >> 5;   // cyp 0..7 -> conv rows 2cyp,2cyp+1
    float a0[C1_OC], a1[C1_OC];
    #pragma unroll
    for (int oc = 0; oc < C1_OC; ++oc) { a0[oc] = b1[oc]; a1[oc] = b1[oc]; }

    #pragma unroll
    for (int c = 0; c < C1_IC; ++c) {
        const float* ib = &in_t[c * T1_ICH + 2 * cx];
        #pragma unroll
        for (int ky = 0; ky < 5; ++ky) {
            const float* r0 = ib + (4 * cyp + ky) * T1_IW;
            const float* r1 = r0 + 2 * T1_IW;
            #pragma unroll
            for (int kx = 0; kx < 5; ++kx) {
                const int kid = (c * 25 + ky * 5 + kx) * 8;
                const float4 wa = *(const float4*)&wlds[kid];
                const float2 wb = *(const float2*)&wlds[kid + 4];
                const float x0 = r0[kx], x1 = r1[kx];
                a0[0] += x0 * wa.x; a0[1] += x0 * wa.y; a0[2] += x0 * wa.z;
                a0[3] += x0 * wa.w; a0[4] += x0 * wb.x; a0[5] += x0 * wb.y;
                a1[0] += x1 * wa.x; a1[1] += x1 * wa.y; a1[2] += x1 * wa.z;
                a1[3] += x1 * wa.w; a1[4] += x1 * wb.x; a1[5] += x1 * wb.y;
            }
        }
    }
    #pragma unroll
    for (int oc = 0; oc < C1_OC; ++oc) {
        out_t[(oc * 16 + 2 * cyp)     * 33 + cx] = fmaxf(a0[oc], 0.f);
        out_t[(oc * 16 + 2 * cyp + 1) * 33 + cx] = fmaxf(a1[oc], 0.f);
    }
    __syncthreads();

    for (int pi = tid; pi < 31 * 15; pi += 256) {
        int pxl = pi % 31, pyl = pi / 31;
        int py = cy0 + pyl, px = cx0 + pxl;
        if (py < P1_H && px < P1_H) {
            #pragma unroll
            for (int oc = 0; oc < C1_OC; ++oc) {
                const float* p = &out_t[(oc * 16 + pyl) * 33 + pxl];
                float m = fmaxf(fmaxf(p[0], p[1]), fmaxf(p[33], p[34]));
                pool1[((b * C1_OC + oc) * P1_H + py) * P1_H + px] = m;
            }
        }
    }
}

// ================= conv2 (3x3 s2 p1) + ReLU + pool(2,1) -> bf16 A =================
// conv tile 32x8 (1 pixel/thread), pool tile 31x7. Grid (2,9,256).
#define T2_IW   65
#define T2_ROWS 17
#define T2_ICH  (T2_IW * T2_ROWS)   // 1105

__global__ __launch_bounds__(256) void conv2_pool2_kernel(
    const float* __restrict__ in, const float* __restrict__ w2,
    const float* __restrict__ b2, __hip_bfloat16* __restrict__ Abf) {
    __shared__ float in_t[C2_IC * T2_ICH];     // 6630 fl = 26.5 KB
    __shared__ float wlds[54 * 16];            // [k][oc pad 16]
    __shared__ float out_t[C2_OC * 8 * 33];    // 15.8 KB

    const int tid = threadIdx.x;
    const int cx0 = blockIdx.x * 31;
    const int cy0 = blockIdx.y * 7;
    const int b   = blockIdx.z;

    for (int f = tid; f < 54 * 16; f += 256) {
        int oc = f & 15, k = f >> 4;
        wlds[f] = (oc < C2_OC) ? w2[oc * 54 + k] : 0.f;
    }
    const int iy0 = 2 * cy0 - 1, ix0 = 2 * cx0 - 1;
    for (int f = tid; f < C2_IC * T2_ICH; f += 256) {
        int ch = f / T2_ICH, rem = f - ch * T2_ICH;
        int row = rem / T2_IW, col = rem - row * T2_IW;
        int iy = iy0 + row, ix = ix0 + col;
        float v = 0.f;
        if ((unsigned)iy < (unsigned)P1_H && (unsigned)ix < (unsigned)P1_H)
            v = in[((b * C2_IC + ch) * P1_H + iy) * P1_H + ix];
        in_t[f] = v;
    }
    __syncthreads();

    const int cx = tid & 31, cy = tid >> 5;
    float acc[C2_OC];
    #pragma unroll
    for (int oc = 0; oc < C2_OC; ++oc) acc[oc] = b2[oc];

    #pragma unroll
    for (int c = 0; c < C2_IC; ++c) {
        const float* ib = &in_t[c * T2_ICH + 2 * cx];
        #pragma unroll
        for (int ky = 0; ky < 3; ++ky) {
            const float* r = ib + (2 * cy + ky) * T2_IW;
            #pragma unroll
            for (int kx = 0; kx < 3; ++kx) {
                const int kid = (c * 9 + ky * 3 + kx) * 16;
                const float4 w0 = *(const float4*)&wlds[kid];
                const float4 w1v = *(const float4*)&wlds[kid + 4];
                const float4 w2v = *(const float4*)&wlds[kid + 8];
                const float4 w3v = *(const float4*)&wlds[kid + 12];
                const float xv = r[kx];
                acc[0]  += xv * w0.x;  acc[1]  += xv * w0.y;
                acc[2]  += xv * w0.z;  acc[3]  += xv * w0.w;
                acc[4]  += xv * w1v.x; acc[5]  += xv * w1v.y;
                acc[6]  += xv * w1v.z; acc[7]  += xv * w1v.w;
                acc[8]  += xv * w2v.x; acc[9]  += xv * w2v.y;
                acc[10] += xv * w2v.z; acc[11] += xv * w2v.w;
                acc[12] += xv * w3v.x; acc[13] += xv * w3v.y;
                acc[14] += xv * w3v.z;
            }
        }
    }
    #pragma unroll
    for (int oc = 0; oc < C2_OC; ++oc)
        out_t[(oc * 8 + cy) * 33 + cx] = fmaxf(acc[oc], 0.f);
    __syncthreads();

    for (int pi = tid; pi < 31 * 7; pi += 256) {
        int pxl = pi % 31, pyl = pi / 31;
        int py = cy0 + pyl, px = cx0 + pxl;
        if (py < P2_H && px < P2_H) {
            #pragma unroll
            for (int oc = 0; oc < C2_OC; ++oc) {
                const float* p = &out_t[(oc * 8 + pyl) * 33 + pxl];
                float m = fmaxf(fmaxf(p[0], p[1]), fmaxf(p[33], p[34]));
                Abf[(size_t)b * KP + (oc * P2_H + py) * P2_H + px] =
                    __float2bfloat16(m);
            }
        }
    }
}

// ================= fc1_w fp32 -> bf16 (into zeroed, K-padded buffer) ======
__global__ __launch_bounds__(256) void wconv_kernel(
    const float* __restrict__ w, __hip_bfloat16* __restrict__ wb) {
    int k = blockIdx.x * 256 + threadIdx.x;
    int n = blockIdx.y;
    if (k < FC1_K)
        wb[(size_t)n * KP + k] = __float2bfloat16(w[(size_t)n * FC1_K + k]);
}

// ================= fc1: bf16 MFMA split-K GEMM -> fp32 partials ===========
// Block 256 thr = 4 waves; wave = 32 m-rows x 128 n. Grid (2 m-tiles, 128 k-chunks).
__global__ __launch_bounds__(256) void fc1_mfma_kernel(
    const __hip_bfloat16* __restrict__ A, const __hip_bfloat16* __restrict__ W,
    float* __restrict__ partial) {
    const int wave = threadIdx.x >> 6, lane = threadIdx.x & 63;
    const int mrow = lane & 15, quad = lane >> 4;
    const int m0 = blockIdx.x * 128 + wave * 32;
    const int k0 = blockIdx.y * FC1_KC;

    f32x4 acc[2][8];
    #pragma unroll
    for (int i = 0; i < 2; ++i)
        #pragma unroll
        for (int j = 0; j < 8; ++j) acc[i][j] = (f32x4){0.f, 0.f, 0.f, 0.f};

    const short* Ap = (const short*)A;
    const short* Wp = (const short*)W;
    for (int ks = 0; ks < FC1_KC; ks += 32) {
        const int kk = k0 + ks + quad * 8;
        const bf16x8 a0 = *(const bf16x8*)(Ap + (size_t)(m0 + mrow) * KP + kk);
        const bf16x8 a1 = *(const bf16x8*)(Ap + (size_t)(m0 + 16 + mrow) * KP + kk);
        #pragma unroll
        for (int nt = 0; nt < 8; ++nt) {
            const bf16x8 bb = *(const bf16x8*)(Wp + (size_t)(nt * 16 + mrow) * KP + kk);
            acc[0][nt] = __builtin_amdgcn_mfma_f32_16x16x32_bf16(a0, bb, acc[0][nt], 0, 0, 0);
            acc[1][nt] = __builtin_amdgcn_mfma_f32_16x16x32_bf16(a1, bb, acc[1][nt], 0, 0, 0);
        }
    }
    float* po = partial + (size_t)blockIdx.y * (256 * 128);
    #pragma unroll
    for (int mt = 0; mt < 2; ++mt)
        #pragma unroll
        for (int nt = 0; nt < 8; ++nt)
            #pragma unroll
            for (int r = 0; r < 4; ++r)
                po[(m0 + mt * 16 + quad * 4 + r) * 128 + nt * 16 + mrow] = acc[mt][nt][r];
}

// ====== tail: split-K reduce + bias/ReLU, fc2, fc3, quantum head, softmax ======
__global__ __launch_bounds__(128) void tail_kernel(
    const float* __restrict__ partial, const float* __restrict__ fc1_b,
    const float* __restrict__ fc2_w, const float* __restrict__ fc2_b,
    const float* __restrict__ fc3_w, const float* __restrict__ fc3_b,
    const float* __restrict__ qw, float* __restrict__ out) {
    __shared__ float h1[FC1_N];
    __shared__ float h2[FC2_N];
    __shared__ float ang[4];
    int b = blockIdx.x;
    int t = threadIdx.x;

    if (t < FC1_N) {
        const float* p = partial + b * 128 + t;
        float sum = 0.f;
        #pragma unroll 4
        for (int s = 0; s < FC1_SPLIT; ++s) sum += p[(size_t)s * (256 * 128)];
        h1[t] = fmaxf(sum + fc1_b[t], 0.f);
    }
    __syncthreads();
    if (t < FC2_N) {
        float acc = fc2_b[t];
        const float* w = fc2_w + t * FC1_N;
        for (int k = 0; k < FC1_N; ++k) acc += h1[k] * w[k];
        h2[t] = fmaxf(acc, 0.f);
    }
    __syncthreads();
    if (t < 4) {
        float acc = fc3_b[t];
        const float* w = fc3_w + t * FC2_N;
        for (int k = 0; k < FC2_N; ++k) acc += h2[k] * w[k];
        ang[t] = acc;
    }
    __syncthreads();
    if (t == 0) {
        float sr[16], si[16];
        #pragma unroll
        for (int i = 0; i < 16; ++i) { sr[i] = 0.f; si[i] = 0.f; }
        sr[0] = 1.f;
        for (int q = 0; q < 4; ++q) {
            float th = ang[q] * 0.5f;
            float c = cosf(th), s = sinf(th);
            int mask = 1 << (3 - q);
            #pragma unroll
            for (int i = 0; i < 16; ++i) {
                if (i & mask) continue;
                int i1 = i | mask;
                float a0r = sr[i], a0i = si[i], a1r = sr[i1], a1i = si[i1];
                sr[i]  = c * a0r + s * a1i;
                si[i]  = c * a0i - s * a1r;
                sr[i1] = c * a1r + s * a0i;
                si[i1] = c * a1i - s * a0r;
            }
        }
        int widx = 0;
        for (int d = 0; d < 2; ++d) {
            for (int q = 0; q < 4; ++q) {
                float th = qw[widx++] * 0.5f;
                float c = cosf(th), s = sinf(th);
                int mask = 1 << (3 - q);
                #pragma unroll
                for (int i = 0; i < 16; ++i) {
                    if (i & mask) continue;
                    int i1 = i | mask;
                    float a0r = sr[i], a0i = si[i], a1r = sr[i1], a1i = si[i1];
                    sr[i]  = c * a0r - s * a1r;
                    si[i]  = c * a0i - s * a1i;
                    sr[i1] = s * a0r + c * a1r;
                    si[i1] = s * a0i + c * a1i;
                }
            }
            for (int q = 0; q < 3; ++q) {
                int m1 = 1 << (3 - q), m2 = 1 << (2 - q);
                #pragma unroll
                for (int i = 0; i < 16; ++i) {
                    if ((i & m1) && (i & m2)) { sr[i] = -sr[i]; si[i] = -si[i]; }
                }
            }
        }
        float l0 = 0.f, l1 = 0.f;
        #pragma unroll
        for (int i = 0; i < 16; ++i) {
            float p = sr[i] * sr[i] + si[i] * si[i];
            l0 += (i & 8) ? -p : p;
            l1 += (i & 4) ? -p : p;
        }
        float m = fmaxf(l0, l1);
        float e0 = expf(l0 - m), e1 = expf(l1 - m);
        float inv = 1.f / (e0 + e1);
        out[b * 2 + 0] = e0 * inv;
        out[b * 2 + 1] = e1 * inv;
    }
}

extern "C" void kernel_launch(void* const* d_in, const int* in_sizes, int n_in,
                              void* d_out, int out_size, void* d_ws, size_t ws_size,
                              hipStream_t stream) {
    const float* x     = (const float*)d_in[0];
    const float* w1    = (const float*)d_in[1];
    const float* b1    = (const float*)d_in[2];
    const float* w2    = (const float*)d_in[3];
    const float* b2    = (const float*)d_in[4];
    const float* fc1_w = (const float*)d_in[5];
    const float* fc1_b = (const float*)d_in[6];
    const float* fc2_w = (const float*)d_in[7];
    const float* fc2_b = (const float*)d_in[8];
    const float* fc3_w = (const float*)d_in[9];
    const float* fc3_b = (const float*)d_in[10];
    const float* qw    = (const float*)d_in[11];
    float* out = (float*)d_out;

    // ws layout:
    //   pool1   fp32 (B,6,123,123)        92,952,576 B
    //   A_bf16  (256, KP)                 29,360,128 B
    //   W_bf16  (128, KP)                 14,680,064 B
    //   partial fp32 (128, 256, 128)      16,777,216 B
    char* ws = (char*)d_ws;
    float*          pool1   = (float*)ws;
    __hip_bfloat16* A_bf16  = (__hip_bfloat16*)(ws + 92952576);
    __hip_bfloat16* W_bf16  = (__hip_bfloat16*)(ws + 92952576 + 29360128);
    float*          partial = (float*)(ws + 92952576 + 29360128 + 14680064);

    // 0. zero W_bf16 (zeros the K-pad so A's poisoned pad contributes 0)
    hipMemsetAsync(W_bf16, 0, (size_t)128 * KP * 2, stream);
    // 1. fc1_w -> bf16
    wconv_kernel<<<dim3((FC1_K + 255) / 256, FC1_N), 256, 0, stream>>>(fc1_w, W_bf16);
    // 2. conv1+pool1
    conv1_pool1_kernel<<<dim3(4, 9, B), 256, 0, stream>>>(x, w1, b1, pool1);
    // 3. conv2+pool2 -> A_bf16 rows
    conv2_pool2_kernel<<<dim3(2, 9, B), 256, 0, stream>>>(pool1, w2, b2, A_bf16);
    // 4. fc1 MFMA split-K
    fc1_mfma_kernel<<<dim3(2, FC1_SPLIT), 256, 0, stream>>>(A_bf16, W_bf16, partial);
    // 5. tail (reduces split-K partials)
    tail_kernel<<<B, 128, 0, stream>>>(partial, fc1_b, fc2_w, fc2_b,
                                       fc3_w, fc3_b, qw, out);
}